// Round 6
// baseline (25771.643 us; speedup 1.0000x reference)
//
#include <hip/hip_runtime.h>
#include <math.h>

#define NSTATES 1024
#define TT      4096
#define DD      20

#define FW_BLOCKS  64
#define FW_THREADS 256
#define JPB  16      // j per block   (FW_BLOCKS * JPB = NSTATES)
#define NSEG 16      // k segments    (JPB * NSEG = FW_THREADS)
#define KSEG 64      // k per segment (NSEG * KSEG = NSTATES)

// workspace layout (bytes)
#define OFF_LAT   ((size_t)0)               // 4 MB  logA transposed: lat[j*N+k] = log(trans[k][j])
#define OFF_E     ((size_t)4 << 20)         // 16 MB emissions E[t*N+n]
#define OFF_COLS  ((size_t)20 << 20)        // 16 MB per-step columns cols[t*N+j]
#define OFF_PTR   ((size_t)36 << 20)        // 8 MB  u16 backpointers, rows 1..T-1
// flags live in bptr row 0 (2 KB, otherwise dead): ring of 8 step-slots x
// 4 replicated copies, each copy on its own 64B line (16-word stride).
// flag word for (step t, copy c) = flag[(t&7)*64 + c*16].

typedef unsigned int u32;
typedef u32 u32x4 __attribute__((ext_vector_type(4)));

#define ALD(p) __hip_atomic_load((p), __ATOMIC_RELAXED, __HIP_MEMORY_SCOPE_AGENT)

__global__ void k_init(u32* __restrict__ fl) {
    // zero the 8x4 flag ring; step-0 slot (idx 0) pre-set to 64 in all 4 copies
    int id = threadIdx.x;                    // 1 block x 512
    if (id < 512) fl[id] = (id == 0 || id == 16 || id == 32 || id == 48) ? 64u : 0u;
}

__global__ void k_logtrans(const float* __restrict__ tr, float* __restrict__ lat) {
    int id = blockIdx.x * 256 + threadIdx.x;        // 1M threads
    int k = id >> 10, j = id & 1023;
    lat[(size_t)j * NSTATES + k] = logf(tr[id]);    // coalesced read, strided write (one-time)
}

__global__ void k_emis(const float* __restrict__ ev, const float* __restrict__ epar,
                       const float* __restrict__ prior, float* __restrict__ E,
                       float* __restrict__ cols) {
    int n = blockIdx.x * 256 + threadIdx.x;         // 4 x 256 = 1024
    int t = blockIdx.y;                             // 0..4095
    const float* ep = epar + (size_t)n * (2 * DD);
    const float* x  = ev + (size_t)t * DD;
    float acc = 0.0f;
    #pragma unroll
    for (int d = 0; d < DD; ++d) {
        float m = ep[2 * d];
        float s = ep[2 * d + 1];
        // faithful to reference: p = (2*pi*s)^(-0.5) * exp(-(x-m)^2/(2*s^2)); logp = log(p)
        float tp   = 6.2831853071795864769f * s;
        float coef = 1.0f / sqrtf(tp);
        float df   = x[d] - m;
        float num  = df * df;
        float den  = 2.0f * (s * s);
        float p    = coef * expf(-num / den);
        acc += logf(p);                             // -inf propagates; values are never NaN
    }
    E[(size_t)t * NSTATES + n] = acc;
    if (t == 0) cols[n] = logf(prior[n]) + acc;     // col0 = log(prior) + logp0
}

// Forward pass, flag-decoupled handoff:
//   publish: 16 lanes atomic-swap their 64B data line (executes at LLC),
//            vmcnt(0), then lanes 0-3 atomic-add the 4 flag copies (release
//            ordering by LLC real-time: data lands before flag lands).
//   detect:  each wave spins sleepless/two-deep on ONE uniform-address flag
//            word (its copy) -> 1 broadcast line-request per ~80cy per wave,
//            so cadence is fast AND traffic is trivial (R4's cadence without
//            R4's contention, which is what the R3/R4/R5 evidence demands).
//   data:    exactly ONE dwordx4 sc1 sweep per thread per step (proven
//            coherent in R5), uncontended since continuous polling is gone.
//   ring:    8 slots, reset slot (t-4)&7 before the vmcnt(0)+add, so the
//            reset is LLC-visible before flag[t] hits 64; max block skew is
//            1 step, so slot reuse at distance 4 is race-free.
__global__ __launch_bounds__(FW_THREADS, 1) void k_forward(
    const float* __restrict__ lat, const float* __restrict__ E,
    float* __restrict__ cols, unsigned short* __restrict__ bptr,
    u32* __restrict__ flag)
{
    // padded [16][68]: row r holds words [r*64, r*64+64) of the prev column.
    __shared__ __align__(16) float prevs[NSEG * 68];
    __shared__ float          smaxw[4][JPB];   // per-wave partials (segs 4w..4w+3)
    __shared__ unsigned short sidxw[4][JPB];
    const int tid  = threadIdx.x;
    const int seg  = tid >> 4;                  // 0..15: k in [seg*64, seg*64+64)
    const int jj   = tid & (JPB - 1);
    const int wav  = tid >> 6;                  // wave id 0..3
    const int j0   = blockIdx.x * JPB;
    const int j    = j0 + jj;
    const float lat00 = lat[0];                 // log trans[0][0], for the j==0 quirk

    // preload this thread's lat slice into registers (loop-invariant, 64 VGPRs)
    float4 latr[16];
    {
        const float* lrow = lat + (size_t)j * NSTATES + seg * KSEG;
        #pragma unroll
        for (int u = 0; u < 16; ++u) latr[u] = *(const float4*)(lrow + u * 4);
    }

    // thread stages its 4 swept words at padded (row tid>>4, col (tid&15)*4)
    float* dstp = &prevs[(tid >> 4) * 68 + (tid & 15) * 4];
    const float* rowp = &prevs[seg * 68];

    for (int t = 1; t < TT; ++t) {
        // E prefetch: issued before the spin; drains under the data sweep's wait.
        float e = E[(size_t)t * NSTATES + j];

        // ---- spin on this wave's flag copy (uniform address -> broadcast).
        // Two-deep pipelined: re-check cadence ~ loop body, not RTT.
        {
            const u32* fp = flag + ((t - 1) & 7) * 64 + wav * 16;
            u32 f0 = ALD(fp);
            for (;;) {
                u32 f1 = ALD(fp);
                if (f0 == 64u) break;
                f0 = ALD(fp);
                if (f1 == 64u) break;
            }
        }

        // ---- single data sweep: this thread's 4 words of the prev column.
        const u32* p = (const u32*)(cols + (size_t)(t - 1) * NSTATES) + tid * 4;
        u32x4 A;
        asm volatile(
            "global_load_dwordx4 %0, %1, off sc1\n\t"
            "s_waitcnt vmcnt(0)"
            : "=&v"(A) : "v"(p) : "memory");
        {
            float4 v;
            v.x = __uint_as_float(A.x);
            v.y = __uint_as_float(A.y);
            v.z = __uint_as_float(A.z);
            v.w = __uint_as_float(A.w);
            *(float4*)dstp = v;                 // padded b128 store, conflict-free
        }
        __syncthreads();                        // barrier 1: staging visible to all

        // ---- scan this thread's 64 k's for its j: first-max (strict >, asc k)
        float best = -__builtin_inff();
        int bidx = seg * KSEG;
        #pragma unroll
        for (int u = 0; u < 16; ++u) {
            float4 q  = *(const float4*)(rowp + u * 4);   // 16-lane broadcast
            float4 wv = latr[u];
            int k0 = seg * KSEG + u * 4;
            float v0 = q.x + wv.x;
            float v1 = q.y + wv.y;
            float v2 = q.z + wv.z;
            float v3 = q.w + wv.w;
            if (v0 > best) { best = v0; bidx = k0;     }
            if (v1 > best) { best = v1; bidx = k0 + 1; }
            if (v2 > best) { best = v2; bidx = k0 + 2; }
            if (v3 > best) { best = v3; bidx = k0 + 3; }
        }

        // ---- combine the wave's 4 segs per j via shfl (disjoint ascending k
        // ranges: tie -> smaller bidx == sequential first-max). No sync.
        {
            float ov = __shfl_xor(best, 16);
            int   oi = __shfl_xor(bidx, 16);
            if (ov > best || (ov == best && oi < bidx)) { best = ov; bidx = oi; }
            ov = __shfl_xor(best, 32);
            oi = __shfl_xor(bidx, 32);
            if (ov > best || (ov == best && oi < bidx)) { best = ov; bidx = oi; }
        }
        if ((tid & 63) < JPB) {                 // one lane per (wave, jj)
            smaxw[wav][jj] = best;
            sidxw[wav][jj] = (unsigned short)bidx;
        }
        __syncthreads();                        // barrier 2: partials visible

        // ---- final 4-deep combine (ascending wave == ascending seg) + publish
        if (tid < JPB) {
            float m = smaxw[0][tid];
            int  mi = sidxw[0][tid];
            #pragma unroll
            for (int ww = 1; ww < 4; ++ww) {
                float v = smaxw[ww][tid];
                if (v > m) { m = v; mi = sidxw[ww][tid]; }
            }
            int jw = j0 + tid;
            // reference quirk: j==0 forced from state 0; prevs[0] (staged by
            // tid 0) is cols[t-1][0].
            float val = (jw == 0) ? (prevs[0] + lat00) : m;
            float out = val + e;                // e: jj == tid for tid < 16
            // fire-and-forget swap: data executes AT the LLC (prompt visibility)
            __hip_atomic_exchange((u32*)(cols + (size_t)t * NSTATES) + jw,
                                  __float_as_uint(out), __ATOMIC_RELAXED,
                                  __HIP_MEMORY_SCOPE_AGENT);
            bptr[(size_t)t * NSTATES + jw] = (unsigned short)mi;
        }
        // reset the slot 4 steps back (safe: all blocks are past it; lands
        // before this step's flag add because it precedes the vmcnt below)
        if (t >= 4 && tid >= 16 && tid < 20)
            __hip_atomic_store(flag + ((t - 4) & 7) * 64 + (tid - 16) * 16, 0u,
                               __ATOMIC_RELAXED, __HIP_MEMORY_SCOPE_AGENT);
        if (tid < 4) {
            // order: data swaps + resets at LLC before the flag add lands
            asm volatile("s_waitcnt vmcnt(0)" ::: "memory");
            __hip_atomic_fetch_add(flag + (t & 7) * 64 + tid * 16, 1u,
                                   __ATOMIC_RELAXED, __HIP_MEMORY_SCOPE_AGENT);
        }
        // no third barrier: prevs rewrite next iter is gated by that iter's
        // flag spin + staging; smaxw reuse is ordered by barrier 1.
    }
}

#define BTC 16  // ptr rows per LDS chunk; 2 buffers x 16 rows x 2KB = 64 KB
__global__ void k_backtrace(const float* __restrict__ lastcol,
                            const unsigned short* __restrict__ bptr,
                            int* __restrict__ seq)
{
    __shared__ unsigned short ring[2][BTC][NSTATES];
    __shared__ int s_front;
    const int tid = threadIdx.x;    // 256 threads

    // last = first-max argmax over final column (wave 0)
    if (tid < 64) {
        float best = -__builtin_inff();
        int bi = 0;
        for (int n2 = tid; n2 < NSTATES; n2 += 64) {
            float v = lastcol[n2];
            if (v > best) { best = v; bi = n2; }
        }
        #pragma unroll
        for (int off = 32; off > 0; off >>= 1) {
            float ov = __shfl_xor(best, off);
            int   oi = __shfl_xor(bi, off);
            if (ov > best || (ov == best && oi < bi)) { best = ov; bi = oi; }
        }
        if (tid == 0) { seq[TT] = bi; seq[TT - 1] = bi; s_front = bi; }
    }
    __syncthreads();

    // chunks descend: chunk c covers rows rhi=TT-1-c*BTC .. max(rhi-BTC+1, 1).
    // Double-buffered: 255 threads stage chunk c+1 while lane 0 chases chunk c.
    auto stage = [&](int c, int buf, int t0, int stride) {
        int rhi = TT - 1 - c * BTC;
        int rlo = rhi - (BTC - 1); if (rlo < 1) rlo = 1;
        int n4 = (rhi - rlo + 1) * 128;                 // uint4 per chunk
        uint4* dst = (uint4*)&ring[buf][0][0];
        for (int idx = t0; idx < n4; idx += stride) {
            int ro = idx >> 7, wo = idx & 127;
            dst[idx] = ((const uint4*)(bptr + (size_t)(rhi - ro) * NSTATES))[wo];
        }
    };
    const int nc = (TT - 1 + BTC - 1) / BTC;            // 256
    stage(0, 0, tid, 256);
    __syncthreads();
    for (int c = 0; c < nc; ++c) {
        int buf = c & 1;
        if (tid != 0) {
            if (c + 1 < nc) stage(c + 1, buf ^ 1, tid - 1, 255);
        } else {
            int rhi = TT - 1 - c * BTC;
            int rlo = rhi - (BTC - 1); if (rlo < 1) rlo = 1;
            int front = s_front;
            for (int r = rhi; r >= rlo; --r) {
                front = (int)ring[buf][rhi - r][front];
                seq[r - 1] = front;
            }
            s_front = front;
        }
        __syncthreads();
    }
}

extern "C" void kernel_launch(void* const* d_in, const int* in_sizes, int n_in,
                              void* d_out, int out_size, void* d_ws, size_t ws_size,
                              hipStream_t stream) {
    const float* ev    = (const float*)d_in[0];   // [T, D]
    const float* prior = (const float*)d_in[1];   // [N]
    const float* tr    = (const float*)d_in[2];   // [N, N]
    const float* epar  = (const float*)d_in[3];   // [N, D, 2]
    int* seq = (int*)d_out;                       // [T+1]
    char* ws = (char*)d_ws;
    float* lat  = (float*)(ws + OFF_LAT);
    float* E    = (float*)(ws + OFF_E);
    float* cols = (float*)(ws + OFF_COLS);
    unsigned short* bptr = (unsigned short*)(ws + OFF_PTR);
    u32* flag = (u32*)(ws + OFF_PTR);             // bptr row 0 (dead) = flag ring

    k_init<<<1, 512, 0, stream>>>(flag);          // flag ring init (no 16MB fill)
    k_logtrans<<<4096, 256, 0, stream>>>(tr, lat);
    k_emis<<<dim3(4, TT), 256, 0, stream>>>(ev, epar, prior, E, cols);
    k_forward<<<FW_BLOCKS, FW_THREADS, 0, stream>>>(lat, E, cols, bptr, flag);
    k_backtrace<<<1, 256, 0, stream>>>(cols + (size_t)(TT - 1) * NSTATES, bptr, seq);
}

// Round 7
// 10381.986 us; speedup vs baseline: 2.4823x; 2.4823x over previous
//
#include <hip/hip_runtime.h>
#include <math.h>

#define NSTATES 1024
#define TT      4096
#define DD      20

#define FW_BLOCKS  64
#define FW_THREADS 256
#define JPB  16      // j per block   (FW_BLOCKS * JPB = NSTATES)
#define NSEG 16      // k segments    (JPB * NSEG = FW_THREADS)
#define KSEG 64      // k per segment (NSEG * KSEG = NSTATES)

#define SENT 0x7FC00000u   // canonical NaN: computed column values are never NaN

// workspace layout (bytes)
#define OFF_LAT   ((size_t)0)               // 4 MB  logA transposed: lat[j*N+k] = log(trans[k][j])
#define OFF_E     ((size_t)4 << 20)         // 16 MB emissions E[t*N+n]
#define OFF_COLS  ((size_t)20 << 20)        // 16 MB per-step columns cols[t*N+j]
#define OFF_PTR   ((size_t)36 << 20)        // 8 MB  u16 backpointers, rows 1..T-1

typedef unsigned int u32;

__global__ void k_init(uint4* __restrict__ cols4) {
    // fill 16 MB of cols with the sentinel (4M words = 1M uint4)
    int id = blockIdx.x * 256 + threadIdx.x;
    cols4[id] = make_uint4(SENT, SENT, SENT, SENT);
}

__global__ void k_logtrans(const float* __restrict__ tr, float* __restrict__ lat) {
    int id = blockIdx.x * 256 + threadIdx.x;        // 1M threads
    int k = id >> 10, j = id & 1023;
    lat[(size_t)j * NSTATES + k] = logf(tr[id]);    // coalesced read, strided write (one-time)
}

__global__ void k_emis(const float* __restrict__ ev, const float* __restrict__ epar,
                       const float* __restrict__ prior, float* __restrict__ E,
                       float* __restrict__ cols) {
    int n = blockIdx.x * 256 + threadIdx.x;         // 4 x 256 = 1024
    int t = blockIdx.y;                             // 0..4095
    const float* ep = epar + (size_t)n * (2 * DD);
    const float* x  = ev + (size_t)t * DD;
    float acc = 0.0f;
    #pragma unroll
    for (int d = 0; d < DD; ++d) {
        float m = ep[2 * d];
        float s = ep[2 * d + 1];
        // faithful to reference: p = (2*pi*s)^(-0.5) * exp(-(x-m)^2/(2*s^2)); logp = log(p)
        float tp   = 6.2831853071795864769f * s;
        float coef = 1.0f / sqrtf(tp);
        float df   = x[d] - m;
        float num  = df * df;
        float den  = 2.0f * (s * s);
        float p    = coef * expf(-num / den);
        acc += logf(p);                             // -inf propagates; values are never NaN
    }
    E[(size_t)t * NSTATES + n] = acc;
    if (t == 0) cols[n] = logf(prior[n]) + acc;     // col0 = log(prior) + logp0 (overwrites sentinel)
}

// Forward pass: the round-3 kernel VERBATIM (best measured: 9315 us).
// Four protocol experiments (faster cadence, 4x less traffic, flag/data
// decoupling, intra-block trimming) all regressed or were null -> this
// configuration is a verified local optimum for the LLC-mediated handoff.
__global__ __launch_bounds__(FW_THREADS, 1) void k_forward(
    const float* __restrict__ lat, const float* __restrict__ E,
    float* __restrict__ cols, unsigned short* __restrict__ bptr)
{
    // padded [16][68]: row r holds words [r*64, r*64+64) of the prev column.
    __shared__ __align__(16) float prevs[NSEG * 68];
    __shared__ float          smaxw[4][JPB];   // per-wave partials (segs 4w..4w+3)
    __shared__ unsigned short sidxw[4][JPB];
    const int tid  = threadIdx.x;
    const int seg  = tid >> 4;                  // 0..15: k in [seg*64, seg*64+64)
    const int jj   = tid & (JPB - 1);
    const int wav  = tid >> 6;                  // wave id 0..3 (holds segs 4w..4w+3)
    const int j0   = blockIdx.x * JPB;
    const int j    = j0 + jj;
    const float lat00 = lat[0];                 // log trans[0][0], for the j==0 quirk

    // preload this thread's lat slice into registers (loop-invariant, 64 VGPRs)
    float4 latr[16];
    {
        const float* lrow = lat + (size_t)j * NSTATES + seg * KSEG;
        #pragma unroll
        for (int u = 0; u < 16; ++u) latr[u] = *(const float4*)(lrow + u * 4);
    }

    // thread stages its 4 polled words at padded (row tid>>4, col (tid&15)*4)
    float* dstp = &prevs[(tid >> 4) * 68 + (tid & 15) * 4];
    const float* rowp = &prevs[seg * 68];

    for (int t = 1; t < TT; ++t) {
        // E prefetch: issued before the poll; drains under the poll's wait.
        float e = E[(size_t)t * NSTATES + j];

        // ---- poll previous column: 4 relaxed agent-scope word loads/thread,
        // per-thread exit (the proven protocol).
        const u32* p = (const u32*)(cols + (size_t)(t - 1) * NSTATES) + tid * 4;
        u32 w0, w1, w2, w3;
        for (;;) {
            w0 = __hip_atomic_load(p + 0, __ATOMIC_RELAXED, __HIP_MEMORY_SCOPE_AGENT);
            w1 = __hip_atomic_load(p + 1, __ATOMIC_RELAXED, __HIP_MEMORY_SCOPE_AGENT);
            w2 = __hip_atomic_load(p + 2, __ATOMIC_RELAXED, __HIP_MEMORY_SCOPE_AGENT);
            w3 = __hip_atomic_load(p + 3, __ATOMIC_RELAXED, __HIP_MEMORY_SCOPE_AGENT);
            if (w0 != SENT && w1 != SENT && w2 != SENT && w3 != SENT) break;
            __builtin_amdgcn_s_sleep(1);
        }
        {
            float4 v;
            v.x = __uint_as_float(w0);
            v.y = __uint_as_float(w1);
            v.z = __uint_as_float(w2);
            v.w = __uint_as_float(w3);
            *(float4*)dstp = v;                 // padded b128 store, conflict-free
        }
        __syncthreads();                        // barrier 1: staging visible to all

        // ---- scan this thread's 64 k's for its j: first-max (strict >, asc k)
        float best = -__builtin_inff();
        int bidx = seg * KSEG;
        #pragma unroll
        for (int u = 0; u < 16; ++u) {
            float4 q  = *(const float4*)(rowp + u * 4);   // 16-lane broadcast
            float4 wv = latr[u];
            int k0 = seg * KSEG + u * 4;
            float v0 = q.x + wv.x;
            float v1 = q.y + wv.y;
            float v2 = q.z + wv.z;
            float v3 = q.w + wv.w;
            if (v0 > best) { best = v0; bidx = k0;     }
            if (v1 > best) { best = v1; bidx = k0 + 1; }
            if (v2 > best) { best = v2; bidx = k0 + 2; }
            if (v3 > best) { best = v3; bidx = k0 + 3; }
        }

        // ---- combine the wave's 4 segs per j via shfl (disjoint ascending k
        // ranges: tie -> smaller bidx == sequential first-max). No sync.
        {
            float ov = __shfl_xor(best, 16);
            int   oi = __shfl_xor(bidx, 16);
            if (ov > best || (ov == best && oi < bidx)) { best = ov; bidx = oi; }
            ov = __shfl_xor(best, 32);
            oi = __shfl_xor(bidx, 32);
            if (ov > best || (ov == best && oi < bidx)) { best = ov; bidx = oi; }
        }
        if ((tid & 63) < JPB) {                 // one lane per (wave, jj)
            smaxw[wav][jj] = best;
            sidxw[wav][jj] = (unsigned short)bidx;
        }
        __syncthreads();                        // barrier 2: partials visible

        // ---- final 4-deep combine (ascending wave == ascending seg) + publish
        if (tid < JPB) {
            float m = smaxw[0][tid];
            int  mi = sidxw[0][tid];
            #pragma unroll
            for (int ww = 1; ww < 4; ++ww) {
                float v = smaxw[ww][tid];
                if (v > m) { m = v; mi = sidxw[ww][tid]; }
            }
            int jw = j0 + tid;
            // reference quirk: j==0 forced from state 0; prevs[0] (staged by
            // tid 0, wave 0 -- not yet overwritten) is cols[t-1][0].
            float val = (jw == 0) ? (prevs[0] + lat00) : m;
            float out = val + e;                // e: jj == tid for tid < 16
            __hip_atomic_store((u32*)(cols + (size_t)t * NSTATES) + jw,
                               __float_as_uint(out), __ATOMIC_RELAXED,
                               __HIP_MEMORY_SCOPE_AGENT);
            bptr[(size_t)t * NSTATES + jw] = (unsigned short)mi;
        }
        // no third barrier: next iteration's staging only overwrites prevs rows
        // whose readers (scans) completed before barrier 2; smaxw reuse is
        // ordered by the next iteration's barrier 1.
    }
}

// Double-buffered backtrace (verified correct in round 6): 255 threads stage
// chunk c+1 from HBM while lane 0 chases chunk c through LDS.
#define BTC 16  // ptr rows per LDS chunk; 2 buffers x 16 rows x 2KB = 64 KB
__global__ void k_backtrace(const float* __restrict__ lastcol,
                            const unsigned short* __restrict__ bptr,
                            int* __restrict__ seq)
{
    __shared__ unsigned short ring[2][BTC][NSTATES];
    __shared__ int s_front;
    const int tid = threadIdx.x;    // 256 threads

    // last = first-max argmax over final column (wave 0)
    if (tid < 64) {
        float best = -__builtin_inff();
        int bi = 0;
        for (int n2 = tid; n2 < NSTATES; n2 += 64) {
            float v = lastcol[n2];
            if (v > best) { best = v; bi = n2; }
        }
        #pragma unroll
        for (int off = 32; off > 0; off >>= 1) {
            float ov = __shfl_xor(best, off);
            int   oi = __shfl_xor(bi, off);
            if (ov > best || (ov == best && oi < bi)) { best = ov; bi = oi; }
        }
        if (tid == 0) { seq[TT] = bi; seq[TT - 1] = bi; s_front = bi; }
    }
    __syncthreads();

    // chunks descend: chunk c covers rows rhi=TT-1-c*BTC .. max(rhi-BTC+1, 1).
    auto stage = [&](int c, int buf, int t0, int stride) {
        int rhi = TT - 1 - c * BTC;
        int rlo = rhi - (BTC - 1); if (rlo < 1) rlo = 1;
        int n4 = (rhi - rlo + 1) * 128;                 // uint4 per chunk
        uint4* dst = (uint4*)&ring[buf][0][0];
        for (int idx = t0; idx < n4; idx += stride) {
            int ro = idx >> 7, wo = idx & 127;
            dst[idx] = ((const uint4*)(bptr + (size_t)(rhi - ro) * NSTATES))[wo];
        }
    };
    const int nc = (TT - 1 + BTC - 1) / BTC;            // 256
    stage(0, 0, tid, 256);
    __syncthreads();
    for (int c = 0; c < nc; ++c) {
        int buf = c & 1;
        if (tid != 0) {
            if (c + 1 < nc) stage(c + 1, buf ^ 1, tid - 1, 255);
        } else {
            int rhi = TT - 1 - c * BTC;
            int rlo = rhi - (BTC - 1); if (rlo < 1) rlo = 1;
            int front = s_front;
            for (int r = rhi; r >= rlo; --r) {
                front = (int)ring[buf][rhi - r][front];
                seq[r - 1] = front;
            }
            s_front = front;
        }
        __syncthreads();
    }
}

extern "C" void kernel_launch(void* const* d_in, const int* in_sizes, int n_in,
                              void* d_out, int out_size, void* d_ws, size_t ws_size,
                              hipStream_t stream) {
    const float* ev    = (const float*)d_in[0];   // [T, D]
    const float* prior = (const float*)d_in[1];   // [N]
    const float* tr    = (const float*)d_in[2];   // [N, N]
    const float* epar  = (const float*)d_in[3];   // [N, D, 2]
    int* seq = (int*)d_out;                       // [T+1]
    char* ws = (char*)d_ws;
    float* lat  = (float*)(ws + OFF_LAT);
    float* E    = (float*)(ws + OFF_E);
    float* cols = (float*)(ws + OFF_COLS);
    unsigned short* bptr = (unsigned short*)(ws + OFF_PTR);

    k_init<<<4096, 256, 0, stream>>>((uint4*)cols);              // sentinel-fill 16 MB
    k_logtrans<<<4096, 256, 0, stream>>>(tr, lat);
    k_emis<<<dim3(4, TT), 256, 0, stream>>>(ev, epar, prior, E, cols);
    k_forward<<<FW_BLOCKS, FW_THREADS, 0, stream>>>(lat, E, cols, bptr);
    k_backtrace<<<1, 256, 0, stream>>>(cols + (size_t)(TT - 1) * NSTATES, bptr, seq);
}